// Round 4
// baseline (226.101 us; speedup 1.0000x reference)
//
#include <hip/hip_runtime.h>
#include <math.h>

// PCEN: x[B=64, C=128, T=4000] fp32.
// smooth[0]=x[0]; smooth[t]=(1-s)*smooth[t-1]+s*x[t], s=0.025
// out = sqrt(x/(smooth+1e-6)^0.98 + 2) - sqrt(2)
//
// One WAVE per channel, coalesced intra-wave layout, NO LDS / NO barriers.
// Lane l owns float4s {l, l+64, ..., l+960} (16 mini-chunks of 4 elems, scan
// order m = 64k + l) -> every global access is lane-dense (1 KB/instr).
// Per-chunk decay is the constant 0.975^4 (tail chunks are globally last, so
// constant-A is exact) -> constant-coefficient shuffle scan: 6 steps x 16
// interleaved segments, 1 shuffle + 1 predicated fma each. Cross-segment
// chain via lane-63 broadcasts + serial fma. Epilogue uses hardware
// transcendentals (v_log/v_exp/v_rsq).

constexpr int   TLEN = 4000;
constexpr int   NF4  = 1000;
constexpr float S_C  = 0.025f;
constexpr float A_1  = 1.0f - S_C;

constexpr float fpow(float b, int n) {
    float r = 1.0f;
    for (int i = 0; i < n; ++i) r *= b;
    return r;
}
constexpr float A_2   = fpow(A_1, 2);
constexpr float A_3   = fpow(A_1, 3);
constexpr float A_4   = fpow(A_1, 4);     // per-chunk decay
constexpr float P4    = fpow(A_1, 4);     // a4^1   (lane-decay table)
constexpr float P8    = fpow(A_1, 8);     // a4^2
constexpr float P16   = fpow(A_1, 16);    // a4^4
constexpr float P32   = fpow(A_1, 32);    // a4^8
constexpr float P64   = fpow(A_1, 64);    // a4^16
constexpr float P128  = fpow(A_1, 128);   // a4^32
constexpr float A_256 = fpow(A_1, 256);   // a4^64: whole-segment decay

constexpr float ALPHA = 0.98f;
constexpr float EPS_C = 1e-6f;
constexpr float SQRT2 = 1.41421356237309515f;

__device__ __forceinline__ float pcen_elem(float x, float sm) {
    float t = sm + EPS_C;
    float pw = exp2f(-ALPHA * __log2f(t));   // t^-alpha  (v_log_f32 + v_exp_f32)
    float y  = fmaf(x, pw, 2.0f);            // >= 2, rsq-safe
    return y * __frsqrt_rn(y) - SQRT2;       // sqrt(y) - sqrt(2)
}

__global__ __launch_bounds__(256) void pcen_kernel(const float* __restrict__ x,
                                                   float* __restrict__ out) {
    const int tid  = threadIdx.x;
    const int lane = tid & 63;
    const int wv   = tid >> 6;
    const int ch   = blockIdx.x * 4 + wv;          // one wave per channel

    const size_t  base = (size_t)ch * TLEN;
    const float4* __restrict__ x4 = (const float4*)(x + base);
    float4*       __restrict__ o4 = (float4*)(out + base);

    // ---- 16 lane-dense float4 loads (all in flight) ----
    float4 v[16];
#pragma unroll
    for (int k = 0; k < 16; ++k) {
        int f4 = 64 * k + lane;
        v[k] = (f4 < NF4) ? x4[f4] : make_float4(0.f, 0.f, 0.f, 0.f);
    }

    // ---- per-chunk zero-init value B (chunk map: sm -> A_4*sm + B) ----
    float B[16];
#pragma unroll
    for (int k = 0; k < 16; ++k) {
        float4 r  = v[k];
        float  b0 = (k == 0 && lane == 0) ? r.x : S_C * r.x;  // smooth[0]=x[0]
        B[k] = fmaf(A_3, b0, S_C * fmaf(A_2, r.y, fmaf(A_1, r.z, r.w)));
    }

    // ---- constant-coefficient inclusive scan over lanes, 16 segments ----
    // step d: B[l] += a4^d * B[l-d]   (l >= d)
    constexpr float CD[6] = {P4, P8, P16, P32, P64, P128};
#pragma unroll
    for (int s = 0; s < 6; ++s) {
        const int   d = 1 << s;
        const float c = CD[s];
        float Bp[16];
#pragma unroll
        for (int k = 0; k < 16; ++k) Bp[k] = __shfl_up(B[k], d);
        if (lane >= d) {
#pragma unroll
            for (int k = 0; k < 16; ++k) B[k] = fmaf(c, Bp[k], B[k]);
        }
    }

    // ---- per-lane decay a4^lane from bit-select table ----
    float p = 1.0f;
    if (lane & 1)  p *= P4;
    if (lane & 2)  p *= P8;
    if (lane & 4)  p *= P16;
    if (lane & 8)  p *= P32;
    if (lane & 16) p *= P64;
    if (lane & 32) p *= P128;

    // ---- chain segments, replay, epilogue, dense store ----
    float e = 0.0f;                                // value entering segment k
#pragma unroll
    for (int k = 0; k < 16; ++k) {
        float Bx = __shfl_up(B[k], 1);             // lane-exclusive within seg
        if (lane == 0) Bx = 0.0f;
        float sm = fmaf(p, e, Bx);                 // value entering this chunk

        float4 r  = v[k];
        float  b0 = (k == 0 && lane == 0) ? r.x : S_C * r.x;
        float  s0 = fmaf(A_1, sm, b0);
        float  s1 = fmaf(A_1, s0, S_C * r.y);
        float  s2 = fmaf(A_1, s1, S_C * r.z);
        float  s3 = fmaf(A_1, s2, S_C * r.w);

        float4 o;
        o.x = pcen_elem(r.x, s0);
        o.y = pcen_elem(r.y, s1);
        o.z = pcen_elem(r.z, s2);
        o.w = pcen_elem(r.w, s3);

        int f4 = 64 * k + lane;
        if (f4 < NF4) o4[f4] = o;

        float T = __shfl(B[k], 63);                // segment total
        e = fmaf(A_256, e, T);                     // advance entering value
    }
}

extern "C" void kernel_launch(void* const* d_in, const int* in_sizes, int n_in,
                              void* d_out, int out_size, void* d_ws, size_t ws_size,
                              hipStream_t stream) {
    const float* x   = (const float*)d_in[0];
    float*       out = (float*)d_out;
    const int nch    = in_sizes[0] / TLEN;   // 8192 channels
    pcen_kernel<<<nch / 4, 256, 0, stream>>>(x, out);
}